// Round 3
// baseline (480.360 us; speedup 1.0000x reference)
//
#include <hip/hip_runtime.h>
#include <hip/hip_bf16.h>

typedef unsigned int uint32;

__device__ __forceinline__ unsigned short f2bf(float f) {
    unsigned int u = __float_as_uint(f);
    unsigned int r = (u + 0x7FFFu + ((u >> 16) & 1u)) >> 16;
    return (unsigned short)r;
}
__device__ __forceinline__ float bf_lo(uint32 v) {
    return __uint_as_float(v << 16);
}
__device__ __forceinline__ float bf_hi(uint32 v) {
    return __uint_as_float(v & 0xFFFF0000u);
}

// ---------------- degree count (4 edges/thread) ----------------
__global__ __launch_bounds__(256) void count_deg(const int* __restrict__ dst,
                                                 int* __restrict__ deg, int E) {
    int i = (blockIdx.x * blockDim.x + threadIdx.x) * 4;
    if (i + 4 <= E) {
        int4 d = *(const int4*)(&dst[i]);
        atomicAdd(&deg[d.x], 1);
        atomicAdd(&deg[d.y], 1);
        atomicAdd(&deg[d.z], 1);
        atomicAdd(&deg[d.w], 1);
    } else {
        for (int j = i; j < E; ++j) atomicAdd(&deg[dst[j]], 1);
    }
}

// ---------------- exclusive scan (3 kernels); scan1 also writes dinv ----------
#define SCAN_BLK 1024

__global__ __launch_bounds__(256) void scan1(const int* __restrict__ deg,
                                             int* __restrict__ rp,
                                             float* __restrict__ dinv,
                                             int* __restrict__ bsum, int N) {
    __shared__ int sdata[256];
    int t = threadIdx.x;
    int base = blockIdx.x * SCAN_BLK + t * 4;
    int v[4];
    int s = 0;
#pragma unroll
    for (int j = 0; j < 4; ++j) {
        int idx = base + j;
        v[j] = (idx < N) ? deg[idx] : 0;
        if (idx < N) dinv[idx] = rsqrtf((float)v[j] + 1.0f);
        s += v[j];
    }
    sdata[t] = s;
    __syncthreads();
    for (int off = 1; off < 256; off <<= 1) {
        int y = (t >= off) ? sdata[t - off] : 0;
        __syncthreads();
        sdata[t] += y;
        __syncthreads();
    }
    int incl = sdata[t];
    int run = incl - s;
#pragma unroll
    for (int j = 0; j < 4; ++j) {
        int idx = base + j;
        if (idx < N) rp[idx] = run;
        run += v[j];
    }
    if (t == 255) bsum[blockIdx.x] = incl;
}

__global__ __launch_bounds__(1024) void scan2(int* __restrict__ bsum, int NB) {
    __shared__ int sd[1024];
    int t = threadIdx.x;
    int v = (t < NB) ? bsum[t] : 0;
    sd[t] = v;
    __syncthreads();
    for (int off = 1; off < 1024; off <<= 1) {
        int y = (t >= off) ? sd[t - off] : 0;
        __syncthreads();
        sd[t] += y;
        __syncthreads();
    }
    if (t < NB) bsum[t] = sd[t] - v;
}

__global__ __launch_bounds__(256) void scan3(int* __restrict__ rp,
                                             int* __restrict__ cur,
                                             const int* __restrict__ bsum,
                                             int N, int E) {
    int i = blockIdx.x * blockDim.x + threadIdx.x;
    if (i < N) {
        int v = rp[i] + bsum[i / SCAN_BLK];
        rp[i] = v;
        cur[i] = v;
    }
    if (i == 0) rp[N] = E;
}

// ---------------- CSR fill (4 edges/thread, cursor = copy of rp) ----------------
__global__ __launch_bounds__(256) void fill_csr(const int* __restrict__ src,
                                                const int* __restrict__ dst,
                                                int* __restrict__ cur,
                                                int* __restrict__ col, int E) {
    int i = (blockIdx.x * blockDim.x + threadIdx.x) * 4;
    if (i + 4 <= E) {
        int4 s = *(const int4*)(&src[i]);
        int4 d = *(const int4*)(&dst[i]);
        col[atomicAdd(&cur[d.x], 1)] = s.x;
        col[atomicAdd(&cur[d.y], 1)] = s.y;
        col[atomicAdd(&cur[d.z], 1)] = s.z;
        col[atomicAdd(&cur[d.w], 1)] = s.w;
    } else {
        for (int j = i; j < E; ++j) col[atomicAdd(&cur[dst[j]], 1)] = src[j];
    }
}

// ---- GEMM: y[r][c] = bf16( dinv[r] * (A[r] @ W)[c] ), A fp32 NxK=64 ----
__global__ __launch_bounds__(256) void gemm64_bf16(const float* __restrict__ A,
                                                   const float* __restrict__ W,
                                                   const float* __restrict__ dinv,
                                                   unsigned short* __restrict__ out,
                                                   int N) {
    __shared__ float sW[64][64];
    __shared__ float sX[64][65];
    int t = threadIdx.x;
    for (int i = t; i < 4096; i += 256) sW[i >> 6][i & 63] = W[i];
    int row0 = blockIdx.x * 64;
    for (int i = t; i < 4096; i += 256) {
        int r = i >> 6, c = i & 63;
        int gr = row0 + r;
        sX[r][c] = (gr < N) ? A[(size_t)gr * 64 + c] : 0.f;
    }
    __syncthreads();
    int r = t >> 2;
    int c0 = (t & 3) * 16;
    float acc[16];
#pragma unroll
    for (int j = 0; j < 16; ++j) acc[j] = 0.f;
#pragma unroll
    for (int k = 0; k < 64; ++k) {
        float xv = sX[r][k];
#pragma unroll
        for (int j = 0; j < 16; ++j) acc[j] += xv * sW[k][c0 + j];
    }
    int gr = row0 + r;
    if (gr < N) {
        float dv = dinv[gr];
        unsigned int pk[8];
#pragma unroll
        for (int j = 0; j < 8; ++j) {
            unsigned int lo = f2bf(acc[2 * j] * dv);
            unsigned int hi = f2bf(acc[2 * j + 1] * dv);
            pk[j] = lo | (hi << 16);
        }
        unsigned int* op = (unsigned int*)(&out[(size_t)gr * 64 + c0]);
        *(uint4*)op = make_uint4(pk[0], pk[1], pk[2], pk[3]);
        *(uint4*)(op + 4) = make_uint4(pk[4], pk[5], pk[6], pk[7]);
    }
}

// Packed-gather aggregation core: 2 edges per VMEM instruction.
// Lane L: half = L>>5 selects which edge of a pair, li = L&31 selects the
// dword (2 bf16 channels) within the 128 B row. Self-term rides as a gather
// of row wid on half 0; the odd leftover edge rides on half 1 in the same
// initial predicated load. Returns combined (both halves hold full sums)
// channel sums for channels (2*li, 2*li+1), pre-dinv/bias.
__device__ __forceinline__ void agg_gather(const uint32* __restrict__ yt,
                                           const int* __restrict__ col,
                                           int wid, int e0, int e1,
                                           int li, int half,
                                           float& sx, float& sy) {
    int nb = e1 - e0;
    float ax = 0.f, ay = 0.f, bx = 0.f, by = 0.f;
    float cx = 0.f, cy = 0.f, dx = 0.f, dy = 0.f;
    {
        int r = (half == 0) ? wid : ((nb & 1) ? col[e1 - 1] : -1);
        if (r >= 0) {
            uint32 v = yt[(size_t)r * 32 + li];
            ax += bf_lo(v);
            ay += bf_hi(v);
        }
    }
    int nb2 = nb & ~1;
    int i = 0;
    for (; i + 8 <= nb2; i += 8) {
        int r0 = col[e0 + i + half];
        int r1 = col[e0 + i + 2 + half];
        int r2 = col[e0 + i + 4 + half];
        int r3 = col[e0 + i + 6 + half];
        uint32 v0 = yt[(size_t)r0 * 32 + li];
        uint32 v1 = yt[(size_t)r1 * 32 + li];
        uint32 v2 = yt[(size_t)r2 * 32 + li];
        uint32 v3 = yt[(size_t)r3 * 32 + li];
        ax += bf_lo(v0); ay += bf_hi(v0);
        bx += bf_lo(v1); by += bf_hi(v1);
        cx += bf_lo(v2); cy += bf_hi(v2);
        dx += bf_lo(v3); dy += bf_hi(v3);
    }
    for (; i + 2 <= nb2; i += 2) {
        int r = col[e0 + i + half];
        uint32 v = yt[(size_t)r * 32 + li];
        ax += bf_lo(v);
        ay += bf_hi(v);
    }
    sx = (ax + bx) + (cx + dx);
    sy = (ay + by) + (cy + dy);
    sx += __shfl_xor(sx, 32);
    sy += __shfl_xor(sy, 32);
}

// ---- fused: agg layer1 (packed gather y1) -> relu -> h @ W2 -> y2 bf16 ----
__global__ __launch_bounds__(256) void agg_gemm_kernel(const uint32* __restrict__ y1,
                                                       const int* __restrict__ rp,
                                                       const int* __restrict__ col,
                                                       const float* __restrict__ dinv,
                                                       const float* __restrict__ bias,
                                                       const float* __restrict__ W2,
                                                       unsigned short* __restrict__ y2,
                                                       int N) {
    __shared__ float sW2[64][64];
    int t = threadIdx.x;
    for (int i = t; i < 4096; i += 256) sW2[i >> 6][i & 63] = W2[i];
    __syncthreads();

    int wid = blockIdx.x * 4 + (t >> 6);
    int lane = t & 63;
    if (wid >= N) return;
    int li = lane & 31, half = lane >> 5;
    int e0 = rp[wid], e1 = rp[wid + 1];
    float sx, sy;
    agg_gather(y1, col, wid, e0, e1, li, half, sx, sy);

    float di = dinv[wid];
    float2 bv = *(const float2*)(&bias[2 * li]);
    float hx = sx * di + bv.x; hx = hx > 0.f ? hx : 0.f;
    float hy = sy * di + bv.y; hy = hy > 0.f ? hy : 0.f;

    // unpack to per-lane-channel layout: channel c == lane
    float ha = __shfl(hx, lane >> 1);
    float hb = __shfl(hy, lane >> 1);
    float h = (lane & 1) ? hb : ha;

    // y2 = bf16( di * (h @ W2) )
    float p0 = 0.f, p1 = 0.f;
#pragma unroll
    for (int k = 0; k < 64; k += 2) {
        p0 += __shfl(h, k) * sW2[k][lane];
        p1 += __shfl(h, k + 1) * sW2[k + 1][lane];
    }
    y2[(size_t)wid * 64 + lane] = f2bf((p0 + p1) * di);
}

// ---- agg layer2 (packed gather y2) -> relu -> dot Wfc[:64] -> nv scalar ----
__global__ __launch_bounds__(256) void agg_nv_kernel(const uint32* __restrict__ y2,
                                                     const int* __restrict__ rp,
                                                     const int* __restrict__ col,
                                                     const float* __restrict__ dinv,
                                                     const float* __restrict__ bias,
                                                     const float* __restrict__ wfc,
                                                     float* __restrict__ nv, int N) {
    int t = threadIdx.x;
    int wid = blockIdx.x * 4 + (t >> 6);
    int lane = t & 63;
    if (wid >= N) return;
    int li = lane & 31, half = lane >> 5;
    int e0 = rp[wid], e1 = rp[wid + 1];
    float sx, sy;
    agg_gather(y2, col, wid, e0, e1, li, half, sx, sy);

    float di = dinv[wid];
    float2 bv = *(const float2*)(&bias[2 * li]);
    float hx = sx * di + bv.x; hx = hx > 0.f ? hx : 0.f;
    float hy = sy * di + bv.y; hy = hy > 0.f ? hy : 0.f;
    float2 wv = *(const float2*)(&wfc[2 * li]);
    float p = hx * wv.x + hy * wv.y;
    // both halves hold identical full sums -> reduce over 32 lanes only
#pragma unroll
    for (int off = 16; off; off >>= 1) p += __shfl_down(p, off);
    if (lane == 0) nv[wid] = p;
}

// ---- fused edge-pred + route sum (wave per route) ----
__global__ __launch_bounds__(256) void route_kernel(const float* __restrict__ nv,
                                                    const int* __restrict__ src,
                                                    const float* __restrict__ ea,
                                                    const float* __restrict__ wfc,
                                                    const float* __restrict__ bfc,
                                                    const int* __restrict__ routes,
                                                    float* __restrict__ out, int R) {
    int r = blockIdx.x * 4 + (threadIdx.x >> 6);
    int lane = threadIdx.x & 63;
    if (r >= R) return;
    int s0 = routes[2 * r], s1 = routes[2 * r + 1];
    float w0 = wfc[64], w1 = wfc[65], b = bfc[0];
    float acc = 0.f;
    for (int e = s0 + lane; e < s1; e += 64) {
        float2 a = *(const float2*)(&ea[2 * (size_t)e]);
        acc += nv[src[e]] + a.x * w0 + a.y * w1 + b;
    }
#pragma unroll
    for (int off = 32; off; off >>= 1) acc += __shfl_down(acc, off);
    if (lane == 0) out[r] = acc;
}

extern "C" void kernel_launch(void* const* d_in, const int* in_sizes, int n_in,
                              void* d_out, int out_size, void* d_ws, size_t ws_size,
                              hipStream_t stream) {
    const float* x   = (const float*)d_in[0];
    const float* ea  = (const float*)d_in[1];
    const float* W1  = (const float*)d_in[2];
    const float* b1  = (const float*)d_in[3];
    const float* W2  = (const float*)d_in[4];
    const float* b2  = (const float*)d_in[5];
    const float* Wfc = (const float*)d_in[6];
    const float* bfc = (const float*)d_in[7];
    const int* eidx  = (const int*)d_in[8];
    const int* routes= (const int*)d_in[9];

    int N = in_sizes[0] / 64;
    int E = in_sizes[8] / 2;
    int R = in_sizes[9] / 2;
    const int* src = eidx;
    const int* dst = eidx + E;

    char* ws = (char*)d_ws;
    size_t off = 0;
    auto alloc = [&](size_t bytes) -> void* {
        off = (off + 255) & ~(size_t)255;
        void* p = ws + off;
        off += bytes;
        return p;
    };

    float* dinv = (float*)alloc((size_t)N * 4);
    int*   deg  = (int*)alloc((size_t)N * 4);
    int*   rp   = (int*)alloc((size_t)(N + 1) * 4);
    int*   cur  = (int*)alloc((size_t)N * 4);
    int*   col  = (int*)alloc((size_t)E * 4);
    unsigned short* y1 = (unsigned short*)alloc((size_t)N * 64 * 2);
    unsigned short* y2 = (unsigned short*)alloc((size_t)N * 64 * 2);
    float* nv   = (float*)alloc((size_t)N * 4);
    int*   bsum = (int*)alloc(4096);

    hipMemsetAsync(deg, 0, (size_t)N * 4, stream);

    int eb4 = (E / 4 + 255) / 256 + 1;
    int nb = (N + 255) / 256;
    int nb1024 = (N + SCAN_BLK - 1) / SCAN_BLK;

    count_deg<<<eb4, 256, 0, stream>>>(dst, deg, E);
    scan1<<<nb1024, 256, 0, stream>>>(deg, rp, dinv, bsum, N);
    scan2<<<1, 1024, 0, stream>>>(bsum, nb1024);
    scan3<<<nb, 256, 0, stream>>>(rp, cur, bsum, N, E);
    fill_csr<<<eb4, 256, 0, stream>>>(src, dst, cur, col, E);

    // layer 1 GEMM (dinv-prescaled bf16 table)
    gemm64_bf16<<<(N + 63) / 64, 256, 0, stream>>>(x, W1, dinv, y1, N);
    // layer-1 agg + fused layer-2 GEMM -> y2 table
    agg_gemm_kernel<<<(N + 3) / 4, 256, 0, stream>>>((const uint32*)y1, rp, col, dinv, b1, W2, y2, N);
    // layer-2 agg + fused Wfc[:64] dot -> nv
    agg_nv_kernel<<<(N + 3) / 4, 256, 0, stream>>>((const uint32*)y2, rp, col, dinv, b2, Wfc, nv, N);

    route_kernel<<<(R + 3) / 4, 256, 0, stream>>>(nv, src, ea, Wfc, bfc, routes, (float*)d_out, R);
}

// Round 4
// 471.336 us; speedup vs baseline: 1.0191x; 1.0191x over previous
//
#include <hip/hip_runtime.h>
#include <hip/hip_bf16.h>

typedef unsigned int uint32;

__device__ __forceinline__ unsigned short f2bf(float f) {
    unsigned int u = __float_as_uint(f);
    unsigned int r = (u + 0x7FFFu + ((u >> 16) & 1u)) >> 16;
    return (unsigned short)r;
}
__device__ __forceinline__ float bf_lo(uint32 v) {
    return __uint_as_float(v << 16);
}
__device__ __forceinline__ float bf_hi(uint32 v) {
    return __uint_as_float(v & 0xFFFF0000u);
}

// ---------------- degree count (4 edges/thread) ----------------
__global__ __launch_bounds__(256) void count_deg(const int* __restrict__ dst,
                                                 int* __restrict__ deg, int E) {
    int i = (blockIdx.x * blockDim.x + threadIdx.x) * 4;
    if (i + 4 <= E) {
        int4 d = *(const int4*)(&dst[i]);
        atomicAdd(&deg[d.x], 1);
        atomicAdd(&deg[d.y], 1);
        atomicAdd(&deg[d.z], 1);
        atomicAdd(&deg[d.w], 1);
    } else {
        for (int j = i; j < E; ++j) atomicAdd(&deg[dst[j]], 1);
    }
}

// ---------------- exclusive scan (3 kernels); scan1 also writes dinv ----------
#define SCAN_BLK 1024

__global__ __launch_bounds__(256) void scan1(const int* __restrict__ deg,
                                             int* __restrict__ rp,
                                             float* __restrict__ dinv,
                                             int* __restrict__ bsum, int N) {
    __shared__ int sdata[256];
    int t = threadIdx.x;
    int base = blockIdx.x * SCAN_BLK + t * 4;
    int v[4];
    int s = 0;
#pragma unroll
    for (int j = 0; j < 4; ++j) {
        int idx = base + j;
        v[j] = (idx < N) ? deg[idx] : 0;
        if (idx < N) dinv[idx] = rsqrtf((float)v[j] + 1.0f);
        s += v[j];
    }
    sdata[t] = s;
    __syncthreads();
    for (int off = 1; off < 256; off <<= 1) {
        int y = (t >= off) ? sdata[t - off] : 0;
        __syncthreads();
        sdata[t] += y;
        __syncthreads();
    }
    int incl = sdata[t];
    int run = incl - s;
#pragma unroll
    for (int j = 0; j < 4; ++j) {
        int idx = base + j;
        if (idx < N) rp[idx] = run;
        run += v[j];
    }
    if (t == 255) bsum[blockIdx.x] = incl;
}

__global__ __launch_bounds__(1024) void scan2(int* __restrict__ bsum, int NB) {
    __shared__ int sd[1024];
    int t = threadIdx.x;
    int v = (t < NB) ? bsum[t] : 0;
    sd[t] = v;
    __syncthreads();
    for (int off = 1; off < 1024; off <<= 1) {
        int y = (t >= off) ? sd[t - off] : 0;
        __syncthreads();
        sd[t] += y;
        __syncthreads();
    }
    if (t < NB) bsum[t] = sd[t] - v;
}

__global__ __launch_bounds__(256) void scan3(int* __restrict__ rp,
                                             int* __restrict__ cur,
                                             const int* __restrict__ bsum,
                                             int N, int E) {
    int i = blockIdx.x * blockDim.x + threadIdx.x;
    if (i < N) {
        int v = rp[i] + bsum[i / SCAN_BLK];
        rp[i] = v;
        cur[i] = v;
    }
    if (i == 0) rp[N] = E;
}

// ---------------- CSR fill (4 edges/thread, cursor = copy of rp) ----------------
__global__ __launch_bounds__(256) void fill_csr(const int* __restrict__ src,
                                                const int* __restrict__ dst,
                                                int* __restrict__ cur,
                                                int* __restrict__ col, int E) {
    int i = (blockIdx.x * blockDim.x + threadIdx.x) * 4;
    if (i + 4 <= E) {
        int4 s = *(const int4*)(&src[i]);
        int4 d = *(const int4*)(&dst[i]);
        col[atomicAdd(&cur[d.x], 1)] = s.x;
        col[atomicAdd(&cur[d.y], 1)] = s.y;
        col[atomicAdd(&cur[d.z], 1)] = s.z;
        col[atomicAdd(&cur[d.w], 1)] = s.w;
    } else {
        for (int j = i; j < E; ++j) col[atomicAdd(&cur[dst[j]], 1)] = src[j];
    }
}

// ---- GEMM: y[r][c] = bf16( dinv[r] * (A[r] @ W)[c] ), A fp32 NxK=64 ----
__global__ __launch_bounds__(256) void gemm64_bf16(const float* __restrict__ A,
                                                   const float* __restrict__ W,
                                                   const float* __restrict__ dinv,
                                                   unsigned short* __restrict__ out,
                                                   int N) {
    __shared__ float sW[64][64];
    __shared__ float sX[64][65];
    int t = threadIdx.x;
    for (int i = t; i < 4096; i += 256) sW[i >> 6][i & 63] = W[i];
    int row0 = blockIdx.x * 64;
    for (int i = t; i < 4096; i += 256) {
        int r = i >> 6, c = i & 63;
        int gr = row0 + r;
        sX[r][c] = (gr < N) ? A[(size_t)gr * 64 + c] : 0.f;
    }
    __syncthreads();
    int r = t >> 2;
    int c0 = (t & 3) * 16;
    float acc[16];
#pragma unroll
    for (int j = 0; j < 16; ++j) acc[j] = 0.f;
#pragma unroll
    for (int k = 0; k < 64; ++k) {
        float xv = sX[r][k];
#pragma unroll
        for (int j = 0; j < 16; ++j) acc[j] += xv * sW[k][c0 + j];
    }
    int gr = row0 + r;
    if (gr < N) {
        float dv = dinv[gr];
        unsigned int pk[8];
#pragma unroll
        for (int j = 0; j < 8; ++j) {
            unsigned int lo = f2bf(acc[2 * j] * dv);
            unsigned int hi = f2bf(acc[2 * j + 1] * dv);
            pk[j] = lo | (hi << 16);
        }
        unsigned int* op = (unsigned int*)(&out[(size_t)gr * 64 + c0]);
        *(uint4*)op = make_uint4(pk[0], pk[1], pk[2], pk[3]);
        *(uint4*)(op + 4) = make_uint4(pk[4], pk[5], pk[6], pk[7]);
    }
}

// Deep-MLP packed gather: 16 lanes per row (uint2 = 4 channels each), so one
// VMEM instruction fetches 4 full 128 B rows (4 edges). All column indices
// for a node load in ONE predicated 64-lane read (deg<=64 fast path); the
// node's row-gathers are then mutually independent and issue back-to-back.
// Row list = [self(wid), col[e0..e1)]. After the loop, cross-slot shfl_xor
// reduction leaves every lane holding summed channels 4c..4c+3 (c = lane&15).
__device__ __forceinline__ void agg_gather4(const uint32* __restrict__ yt,
                                            const int* __restrict__ col,
                                            int wid, int e0, int e1,
                                            int lane, float acc[4]) {
    int s = lane >> 4;   // edge slot within batch
    int c = lane & 15;   // chunk: channels 4c..4c+3
    int nb = e1 - e0;
    int ce = e0 + lane;
    int cvl = (ce < e1) ? col[ce] : -1;
    acc[0] = acc[1] = acc[2] = acc[3] = 0.f;
    int m = nb + 1;                 // rows including self
    int mf = m > 65 ? 65 : m;       // fast-path row count (j-1 must be < 64)
    int nbat = (mf + 3) >> 2;

    auto one = [&](int b) {
        int j = 4 * b + s;
        int sl = j - 1;
        int rr = __shfl(cvl, sl < 0 ? 0 : sl);
        int r = (j == 0) ? wid : ((j >= mf) ? -1 : rr);
        if (r >= 0) {
            uint2 v = *(const uint2*)(yt + (size_t)r * 32 + 2 * c);
            acc[0] += bf_lo(v.x); acc[1] += bf_hi(v.x);
            acc[2] += bf_lo(v.y); acc[3] += bf_hi(v.y);
        }
    };
    int b = 0;
    for (; b + 4 <= nbat; b += 4) { one(b); one(b + 1); one(b + 2); one(b + 3); }
    for (; b < nbat; ++b) one(b);

    // rare tail: degree > 64
    for (int e = e0 + 64; e < e1; e += 4) {
        int ee = e + s;
        int r = (ee < e1) ? col[ee] : -1;
        if (r >= 0) {
            uint2 v = *(const uint2*)(yt + (size_t)r * 32 + 2 * c);
            acc[0] += bf_lo(v.x); acc[1] += bf_hi(v.x);
            acc[2] += bf_lo(v.y); acc[3] += bf_hi(v.y);
        }
    }
#pragma unroll
    for (int j = 0; j < 4; ++j) {
        acc[j] += __shfl_xor(acc[j], 16);
        acc[j] += __shfl_xor(acc[j], 32);
    }
}

// ---- fused: agg layer1 (deep-MLP gather y1) -> relu -> h @ W2 -> y2 bf16 ----
__global__ __launch_bounds__(256) void agg_gemm_kernel(const uint32* __restrict__ y1,
                                                       const int* __restrict__ rp,
                                                       const int* __restrict__ col,
                                                       const float* __restrict__ dinv,
                                                       const float* __restrict__ bias,
                                                       const float* __restrict__ W2,
                                                       unsigned short* __restrict__ y2,
                                                       int N) {
    __shared__ float sW2[64][64];
    int t = threadIdx.x;
    for (int i = t; i < 4096; i += 256) sW2[i >> 6][i & 63] = W2[i];
    __syncthreads();

    int wid = blockIdx.x * 4 + (t >> 6);
    int lane = t & 63;
    if (wid >= N) return;
    int c = lane & 15;
    int e0 = rp[wid], e1 = rp[wid + 1];
    float acc[4];
    agg_gather4(y1, rp ? col : col, wid, e0, e1, lane, acc);

    float di = dinv[wid];
    float4 bv = *(const float4*)(&bias[4 * c]);
    float h[4];
    h[0] = acc[0] * di + bv.x; h[0] = h[0] > 0.f ? h[0] : 0.f;
    h[1] = acc[1] * di + bv.y; h[1] = h[1] > 0.f ? h[1] : 0.f;
    h[2] = acc[2] * di + bv.z; h[2] = h[2] > 0.f ? h[2] : 0.f;
    h[3] = acc[3] * di + bv.w; h[3] = h[3] > 0.f ? h[3] : 0.f;

    // y2[lane] = bf16( di * sum_k h[k] * W2[k][lane] ); h[k] lives in lane k>>2, elem k&3
    float p0 = 0.f, p1 = 0.f;
#pragma unroll
    for (int k = 0; k < 64; k += 2) {
        p0 += __shfl(h[k & 3], k >> 2) * sW2[k][lane];
        p1 += __shfl(h[(k + 1) & 3], (k + 1) >> 2) * sW2[k + 1][lane];
    }
    y2[(size_t)wid * 64 + lane] = f2bf((p0 + p1) * di);
}

// ---- agg layer2 (deep-MLP gather y2) -> relu -> dot Wfc[:64] -> nv scalar ----
__global__ __launch_bounds__(256) void agg_nv_kernel(const uint32* __restrict__ y2,
                                                     const int* __restrict__ rp,
                                                     const int* __restrict__ col,
                                                     const float* __restrict__ dinv,
                                                     const float* __restrict__ bias,
                                                     const float* __restrict__ wfc,
                                                     float* __restrict__ nv, int N) {
    int t = threadIdx.x;
    int wid = blockIdx.x * 4 + (t >> 6);
    int lane = t & 63;
    if (wid >= N) return;
    int c = lane & 15;
    int e0 = rp[wid], e1 = rp[wid + 1];
    float acc[4];
    agg_gather4(y2, col, wid, e0, e1, lane, acc);

    float di = dinv[wid];
    float4 bv = *(const float4*)(&bias[4 * c]);
    float4 wv = *(const float4*)(&wfc[4 * c]);
    float p = 0.f;
    float h0 = acc[0] * di + bv.x; p += (h0 > 0.f ? h0 : 0.f) * wv.x;
    float h1 = acc[1] * di + bv.y; p += (h1 > 0.f ? h1 : 0.f) * wv.y;
    float h2 = acc[2] * di + bv.z; p += (h2 > 0.f ? h2 : 0.f) * wv.z;
    float h3 = acc[3] * di + bv.w; p += (h3 > 0.f ? h3 : 0.f) * wv.w;
    // reduce across the 16 chunk-lanes (slot groups already hold copies)
#pragma unroll
    for (int off = 8; off; off >>= 1) p += __shfl_xor(p, off);
    if (lane == 0) nv[wid] = p;
}

// ---- fused edge-pred + route sum (wave per route) ----
__global__ __launch_bounds__(256) void route_kernel(const float* __restrict__ nv,
                                                    const int* __restrict__ src,
                                                    const float* __restrict__ ea,
                                                    const float* __restrict__ wfc,
                                                    const float* __restrict__ bfc,
                                                    const int* __restrict__ routes,
                                                    float* __restrict__ out, int R) {
    int r = blockIdx.x * 4 + (threadIdx.x >> 6);
    int lane = threadIdx.x & 63;
    if (r >= R) return;
    int s0 = routes[2 * r], s1 = routes[2 * r + 1];
    float w0 = wfc[64], w1 = wfc[65], b = bfc[0];
    float acc = 0.f;
    for (int e = s0 + lane; e < s1; e += 64) {
        float2 a = *(const float2*)(&ea[2 * (size_t)e]);
        acc += nv[src[e]] + a.x * w0 + a.y * w1 + b;
    }
#pragma unroll
    for (int off = 32; off; off >>= 1) acc += __shfl_down(acc, off);
    if (lane == 0) out[r] = acc;
}

extern "C" void kernel_launch(void* const* d_in, const int* in_sizes, int n_in,
                              void* d_out, int out_size, void* d_ws, size_t ws_size,
                              hipStream_t stream) {
    const float* x   = (const float*)d_in[0];
    const float* ea  = (const float*)d_in[1];
    const float* W1  = (const float*)d_in[2];
    const float* b1  = (const float*)d_in[3];
    const float* W2  = (const float*)d_in[4];
    const float* b2  = (const float*)d_in[5];
    const float* Wfc = (const float*)d_in[6];
    const float* bfc = (const float*)d_in[7];
    const int* eidx  = (const int*)d_in[8];
    const int* routes= (const int*)d_in[9];

    int N = in_sizes[0] / 64;
    int E = in_sizes[8] / 2;
    int R = in_sizes[9] / 2;
    const int* src = eidx;
    const int* dst = eidx + E;

    char* ws = (char*)d_ws;
    size_t off = 0;
    auto alloc = [&](size_t bytes) -> void* {
        off = (off + 255) & ~(size_t)255;
        void* p = ws + off;
        off += bytes;
        return p;
    };

    float* dinv = (float*)alloc((size_t)N * 4);
    int*   deg  = (int*)alloc((size_t)N * 4);
    int*   rp   = (int*)alloc((size_t)(N + 1) * 4);
    int*   cur  = (int*)alloc((size_t)N * 4);
    int*   col  = (int*)alloc((size_t)E * 4);
    unsigned short* y1 = (unsigned short*)alloc((size_t)N * 64 * 2);
    unsigned short* y2 = (unsigned short*)alloc((size_t)N * 64 * 2);
    float* nv   = (float*)alloc((size_t)N * 4);
    int*   bsum = (int*)alloc(4096);

    hipMemsetAsync(deg, 0, (size_t)N * 4, stream);

    int eb4 = (E / 4 + 255) / 256 + 1;
    int nb = (N + 255) / 256;
    int nb1024 = (N + SCAN_BLK - 1) / SCAN_BLK;

    count_deg<<<eb4, 256, 0, stream>>>(dst, deg, E);
    scan1<<<nb1024, 256, 0, stream>>>(deg, rp, dinv, bsum, N);
    scan2<<<1, 1024, 0, stream>>>(bsum, nb1024);
    scan3<<<nb, 256, 0, stream>>>(rp, cur, bsum, N, E);
    fill_csr<<<eb4, 256, 0, stream>>>(src, dst, cur, col, E);

    // layer 1 GEMM (dinv-prescaled bf16 table)
    gemm64_bf16<<<(N + 63) / 64, 256, 0, stream>>>(x, W1, dinv, y1, N);
    // layer-1 agg + fused layer-2 GEMM -> y2 table
    agg_gemm_kernel<<<(N + 3) / 4, 256, 0, stream>>>((const uint32*)y1, rp, col, dinv, b1, W2, y2, N);
    // layer-2 agg + fused Wfc[:64] dot -> nv
    agg_nv_kernel<<<(N + 3) / 4, 256, 0, stream>>>((const uint32*)y2, rp, col, dinv, b2, Wfc, nv, N);

    route_kernel<<<(R + 3) / 4, 256, 0, stream>>>(nv, src, ea, Wfc, bfc, routes, (float*)d_out, R);
}